// Round 1
// baseline (412.564 us; speedup 1.0000x reference)
//
#include <hip/hip_runtime.h>
#include <hip/hip_bf16.h>

typedef __attribute__((ext_vector_type(8))) short short8;
typedef __attribute__((ext_vector_type(4))) float f32x4;
using u16 = unsigned short;
typedef unsigned int u32;

__device__ __forceinline__ u16 f2bf(float f) {
    u32 u = __builtin_bit_cast(u32, f);
    u32 r = u + 0x7FFFu + ((u >> 16) & 1u);
    return (u16)(r >> 16);
}

__device__ __forceinline__ void async_load16(const void* g, void* l) {
    __builtin_amdgcn_global_load_lds(
        (const __attribute__((address_space(1))) void*)g,
        (__attribute__((address_space(3))) void*)l, 16, 0, 0);
}

// ---------------- weight transpose + f32->bf16 convert: w[K][N] -> wt[N][K] ----------------
__global__ __launch_bounds__(256) void convt_kernel(const float* __restrict__ w,
                                                    u16* __restrict__ wt, int K, int N) {
    __shared__ float tile[32][33];
    int bn = blockIdx.x * 32, bk = blockIdx.y * 32;
    int tx = threadIdx.x & 31, ty = threadIdx.x >> 5;  // 32 x 8
#pragma unroll
    for (int i = 0; i < 4; i++)
        tile[ty + i * 8][tx] = w[(size_t)(bk + ty + i * 8) * N + bn + tx];
    __syncthreads();
#pragma unroll
    for (int i = 0; i < 4; i++)
        wt[(size_t)(bn + ty + i * 8) * K + bk + tx] = f2bf(tile[tx][ty + i * 8]);
}

// ---------------- LayerNorm (fp32 in, bf16 out), one block per row of 1024 ----------------
__global__ __launch_bounds__(256) void ln_kernel(const float* __restrict__ x,
                                                 const float* __restrict__ ga,
                                                 const float* __restrict__ gb,
                                                 u16* __restrict__ out) {
    int row = blockIdx.x;
    const float4* xr = (const float4*)(x + (size_t)row * 1024);
    float4 v = xr[threadIdx.x];
    float s  = v.x + v.y + v.z + v.w;
    float s2 = v.x * v.x + v.y * v.y + v.z * v.z + v.w * v.w;
#pragma unroll
    for (int off = 32; off; off >>= 1) {
        s  += __shfl_down(s, off);
        s2 += __shfl_down(s2, off);
    }
    __shared__ float rs[4], rs2[4];
    int wid = threadIdx.x >> 6, lane = threadIdx.x & 63;
    if (lane == 0) { rs[wid] = s; rs2[wid] = s2; }
    __syncthreads();
    float S  = rs[0] + rs[1] + rs[2] + rs[3];
    float S2 = rs2[0] + rs2[1] + rs2[2] + rs2[3];
    float mean = S * (1.0f / 1024.0f);
    float var  = fmaxf((S2 - 1024.0f * mean * mean) * (1.0f / 1023.0f), 0.0f);
    float scale = ga[0] / (sqrtf(var) + 1e-6f);
    float shift = gb[0] - mean * scale;
    u16 h0 = f2bf(v.x * scale + shift);
    u16 h1 = f2bf(v.y * scale + shift);
    u16 h2 = f2bf(v.z * scale + shift);
    u16 h3 = f2bf(v.w * scale + shift);
    uint2 pv;
    pv.x = (u32)h0 | ((u32)h1 << 16);
    pv.y = (u32)h2 | ((u32)h3 << 16);
    *(uint2*)(out + (size_t)row * 1024 + threadIdx.x * 4) = pv;
}

// ---------------- bf16 GEMM: C[M,N] = A[M,K] @ Bt[N,K]^T + bias (+relu/+resid) ----------------
// 128x128 tile, BK=32, 256 threads = 4 waves (2x2), each wave 64x64 = 4x4 frags of 16x16x32.
template <int OUT_BF16, int RELU, int RESID>
__global__ __launch_bounds__(256) void gemm_bt(const u16* __restrict__ A,
                                               const u16* __restrict__ Bt,
                                               const float* __restrict__ bias,
                                               void* __restrict__ Cout,
                                               const float* __restrict__ resid,
                                               int M, int N, int K) {
    __shared__ u16 As[4096];  // [128][32]
    __shared__ u16 Bs[4096];  // [128][32]
    int tid = threadIdx.x, lane = tid & 63, wid = tid >> 6;
    int l15 = lane & 15, l4 = lane >> 4;
    int rowA0 = blockIdx.x * 128;
    int rowB0 = blockIdx.y * 128;
    int waveM = wid >> 1, waveN = wid & 1;

    // staging: flat bf16 index covered by this thread (16B per lane per inst)
    int fl = tid * 8;
    int r0 = fl >> 5, c0 = fl & 31;
    const u16* gA0 = A + (size_t)(rowA0 + r0) * K + c0;
    const u16* gA1 = A + (size_t)(rowA0 + 64 + r0) * K + c0;
    const u16* gB0 = Bt + (size_t)(rowB0 + r0) * K + c0;
    const u16* gB1 = Bt + (size_t)(rowB0 + 64 + r0) * K + c0;
    u16* lA0 = As + wid * 512;          // wave-uniform LDS bases
    u16* lA1 = As + 2048 + wid * 512;
    u16* lB0 = Bs + wid * 512;
    u16* lB1 = Bs + 2048 + wid * 512;

    f32x4 acc[4][4] = {};

    for (int k0 = 0; k0 < K; k0 += 32) {
        __syncthreads();  // previous tile's reads done
        async_load16(gA0 + k0, lA0);
        async_load16(gA1 + k0, lA1);
        async_load16(gB0 + k0, lB0);
        async_load16(gB1 + k0, lB1);
        __syncthreads();  // drains vmcnt(0): staged data visible

        short8 af[4], bf[4];
#pragma unroll
        for (int m = 0; m < 4; m++)
            af[m] = *(const short8*)&As[(waveM * 64 + m * 16 + l15) * 32 + l4 * 8];
#pragma unroll
        for (int n = 0; n < 4; n++)
            bf[n] = *(const short8*)&Bs[(waveN * 64 + n * 16 + l15) * 32 + l4 * 8];
#pragma unroll
        for (int m = 0; m < 4; m++)
#pragma unroll
            for (int n = 0; n < 4; n++)
                acc[m][n] = __builtin_amdgcn_mfma_f32_16x16x32_bf16(af[m], bf[n], acc[m][n], 0, 0, 0);
    }

#pragma unroll
    for (int m = 0; m < 4; m++) {
        int row = rowA0 + waveM * 64 + m * 16 + l4 * 4;
#pragma unroll
        for (int n = 0; n < 4; n++) {
            int col = rowB0 + waveN * 64 + n * 16 + l15;
            float bc = bias[col];
#pragma unroll
            for (int j = 0; j < 4; j++) {
                float v = acc[m][n][j] + bc;
                if (RELU) v = fmaxf(v, 0.0f);
                if (RESID) v += resid[(size_t)(row + j) * N + col];
                if (OUT_BF16)
                    ((u16*)Cout)[(size_t)(row + j) * N + col] = f2bf(v);
                else
                    ((float*)Cout)[(size_t)(row + j) * N + col] = v;
            }
        }
    }
}

// ---------------- flash attention: qkv[b,s,3*1024] bf16 -> ctx[b,s,1024] bf16 ----------------
// grid (32 q-tiles, 32 b*h), 256 thr = 4 waves, wave handles 16 q-rows; K/V tiles of 64.
__global__ __launch_bounds__(256) void attn_kernel(const u16* __restrict__ qkv,
                                                   const int* __restrict__ mask,
                                                   u16* __restrict__ ctx) {
    const int S = 2048;
    int qt = blockIdx.x;
    int bh = blockIdx.y;
    int b = bh >> 4, h = bh & 15;
    int tid = threadIdx.x;
    int wid = tid >> 6, lane = tid & 63;
    int l15 = lane & 15, l4 = lane >> 4;

    __shared__ u16 Ks[64][72];        // +8 pad: conflict-light b128 reads
    __shared__ u16 Vt[64][72];        // V transposed: Vt[d][s]
    __shared__ u16 Plds[4][16][72];   // per-wave P relayout buffer

    int qrow0 = qt * 64 + wid * 16;
    const u16* qb = qkv + (size_t)(b * S + qrow0) * 3072 + h * 64;
    short8 qf[2];
    qf[0] = *(const short8*)(qb + (size_t)l15 * 3072 + l4 * 8);
    qf[1] = *(const short8*)(qb + (size_t)l15 * 3072 + 32 + l4 * 8);

    f32x4 o[4] = {};
    float m_i[4], l_i[4];
#pragma unroll
    for (int j = 0; j < 4; j++) { m_i[j] = -1e30f; l_i[j] = 0.0f; }
    const int maskbase = b * S;

    for (int kt = 0; kt < 32; ++kt) {
        __syncthreads();
        {   // stage K tile and transposed V tile
            int srow = tid >> 3;
            int d0 = (tid & 7) * 8;
#pragma unroll
            for (int p = 0; p < 2; p++) {
                int sr = p * 32 + srow;
                size_t gr = (size_t)(b * S + kt * 64 + sr) * 3072 + h * 64 + d0;
                short8 kv = *(const short8*)(qkv + gr + 1024);
                *(short8*)&Ks[sr][d0] = kv;
                short8 vv = *(const short8*)(qkv + gr + 2048);
                u16* vsrc = (u16*)&vv;
#pragma unroll
                for (int j = 0; j < 8; j++) Vt[d0 + j][sr] = vsrc[j];
            }
        }
        __syncthreads();

        // QK^T -> scores (C layout: row = l4*4+j, col = kc*16+l15)
        float sc[4][4];
#pragma unroll
        for (int kc = 0; kc < 4; kc++) {
            short8 kf0 = *(const short8*)&Ks[kc * 16 + l15][l4 * 8];
            short8 kf1 = *(const short8*)&Ks[kc * 16 + l15][32 + l4 * 8];
            f32x4 a = {};
            a = __builtin_amdgcn_mfma_f32_16x16x32_bf16(qf[0], kf0, a, 0, 0, 0);
            a = __builtin_amdgcn_mfma_f32_16x16x32_bf16(qf[1], kf1, a, 0, 0, 0);
            int col = kt * 64 + kc * 16 + l15;
            int mk = mask[maskbase + col];
#pragma unroll
            for (int j = 0; j < 4; j++) sc[kc][j] = (mk == 0) ? -1e9f : a[j] * 0.125f;
        }

        // online softmax per q-row
#pragma unroll
        for (int j = 0; j < 4; j++) {
            float tmax = fmaxf(fmaxf(sc[0][j], sc[1][j]), fmaxf(sc[2][j], sc[3][j]));
#pragma unroll
            for (int mm = 8; mm >= 1; mm >>= 1) tmax = fmaxf(tmax, __shfl_xor(tmax, mm, 16));
            float newm = fmaxf(m_i[j], tmax);
            float rescale = __expf(m_i[j] - newm);
            float ps = 0.0f;
#pragma unroll
            for (int kc = 0; kc < 4; kc++) {
                float p = __expf(sc[kc][j] - newm);
                sc[kc][j] = p;
                ps += p;
            }
#pragma unroll
            for (int mm = 8; mm >= 1; mm >>= 1) ps += __shfl_xor(ps, mm, 16);
            l_i[j] = l_i[j] * rescale + ps;
            m_i[j] = newm;
#pragma unroll
            for (int dc = 0; dc < 4; dc++) o[dc][j] *= rescale;
        }

        // P: C-layout -> LDS -> A-layout (within-wave, lockstep, no barrier needed)
#pragma unroll
        for (int j = 0; j < 4; j++)
#pragma unroll
            for (int kc = 0; kc < 4; kc++)
                Plds[wid][l4 * 4 + j][kc * 16 + l15] = f2bf(sc[kc][j]);

        short8 pa0 = *(const short8*)&Plds[wid][l15][l4 * 8];
        short8 pa1 = *(const short8*)&Plds[wid][l15][32 + l4 * 8];
#pragma unroll
        for (int dc = 0; dc < 4; dc++) {
            short8 vf0 = *(const short8*)&Vt[dc * 16 + l15][l4 * 8];
            short8 vf1 = *(const short8*)&Vt[dc * 16 + l15][32 + l4 * 8];
            o[dc] = __builtin_amdgcn_mfma_f32_16x16x32_bf16(pa0, vf0, o[dc], 0, 0, 0);
            o[dc] = __builtin_amdgcn_mfma_f32_16x16x32_bf16(pa1, vf1, o[dc], 0, 0, 0);
        }
    }

#pragma unroll
    for (int j = 0; j < 4; j++) {
        float inv = 1.0f / l_i[j];
        int row = qrow0 + l4 * 4 + j;
        size_t base = (size_t)(b * S + row) * 1024 + h * 64;
#pragma unroll
        for (int dc = 0; dc < 4; dc++)
            ctx[base + dc * 16 + l15] = f2bf(o[dc][j] * inv);
    }
}

// ---------------- launcher ----------------
extern "C" void kernel_launch(void* const* d_in, const int* in_sizes, int n_in,
                              void* d_out, int out_size, void* d_ws, size_t ws_size,
                              hipStream_t stream) {
    const float* x    = (const float*)d_in[0];
    const int*   mask = (const int*)d_in[1];
    const float* wq   = (const float*)d_in[2];
    const float* bq   = (const float*)d_in[3];
    const float* wk   = (const float*)d_in[4];
    const float* bk   = (const float*)d_in[5];
    const float* wv   = (const float*)d_in[6];
    const float* bv   = (const float*)d_in[7];
    const float* wo   = (const float*)d_in[8];
    const float* bo   = (const float*)d_in[9];
    const float* w1   = (const float*)d_in[10];
    const float* b1   = (const float*)d_in[11];
    const float* w2   = (const float*)d_in[12];
    const float* b2   = (const float*)d_in[13];
    const float* ln1a = (const float*)d_in[14];
    const float* ln1b = (const float*)d_in[15];
    const float* ln2a = (const float*)d_in[16];
    const float* ln2b = (const float*)d_in[17];
    float* out = (float*)d_out;

    char* ws = (char*)d_ws;
    // ws layout (bytes); total ~81 MB
    u16*   wqkvt = (u16*)(ws + 0);                  //  6 MB  [3072][1024]
    u16*   wot   = (u16*)(ws + 6291456);            //  2 MB  [1024][1024]
    u16*   w1t   = (u16*)(ws + 8388608);            //  8 MB  [4096][1024]
    u16*   w2t   = (u16*)(ws + 16777216);           //  8 MB  [1024][4096]
    float* bqkv  = (float*)(ws + 25165824);         // 12 KB
    char*  regA  = ws + 26214400;                   // 40 MB region (reused)
    u16*   xn1   = (u16*)(regA + 0);                //  8 MB
    u16*   qkv   = (u16*)(regA + 8388608);          // 24 MB  [4096][3072]
    u16*   ctx   = (u16*)(regA + 33554432);         //  8 MB
    float* x1    = (float*)(ws + 68157440);         // 16 MB
    u16*   xn2   = (u16*)(regA + 0);                // reuse (xn1 dead)
    u16*   ff1   = (u16*)(regA + 8388608);          // reuse (qkv+ctx dead), 32 MB

    dim3 blk(256);

    // weights -> bf16 transposed
    convt_kernel<<<dim3(32, 32), blk, 0, stream>>>(wq, wqkvt, 1024, 1024);
    convt_kernel<<<dim3(32, 32), blk, 0, stream>>>(wk, wqkvt + 1024 * 1024, 1024, 1024);
    convt_kernel<<<dim3(32, 32), blk, 0, stream>>>(wv, wqkvt + 2048 * 1024, 1024, 1024);
    convt_kernel<<<dim3(32, 32), blk, 0, stream>>>(wo, wot, 1024, 1024);
    convt_kernel<<<dim3(128, 32), blk, 0, stream>>>(w1, w1t, 1024, 4096);
    convt_kernel<<<dim3(32, 128), blk, 0, stream>>>(w2, w2t, 4096, 1024);
    hipMemcpyAsync(bqkv, bq, 4096, hipMemcpyDeviceToDevice, stream);
    hipMemcpyAsync(bqkv + 1024, bk, 4096, hipMemcpyDeviceToDevice, stream);
    hipMemcpyAsync(bqkv + 2048, bv, 4096, hipMemcpyDeviceToDevice, stream);

    // LN1 -> fused QKV gemm -> attention -> WO gemm (+residual x)
    ln_kernel<<<dim3(4096), blk, 0, stream>>>(x, ln1a, ln1b, xn1);
    gemm_bt<1, 0, 0><<<dim3(32, 24), blk, 0, stream>>>(xn1, wqkvt, bqkv, qkv, nullptr, 4096, 3072, 1024);
    attn_kernel<<<dim3(32, 32), blk, 0, stream>>>(qkv, mask, ctx);
    gemm_bt<0, 0, 1><<<dim3(32, 8), blk, 0, stream>>>(ctx, wot, bo, x1, x, 4096, 1024, 1024);

    // LN2 -> FFN1 (+relu) -> FFN2 (+residual x1) -> out
    ln_kernel<<<dim3(4096), blk, 0, stream>>>(x1, ln2a, ln2b, xn2);
    gemm_bt<1, 1, 0><<<dim3(32, 32), blk, 0, stream>>>(xn2, w1t, b1, ff1, nullptr, 4096, 4096, 1024);
    gemm_bt<0, 0, 1><<<dim3(32, 8), blk, 0, stream>>>(ff1, w2t, b2, out, x1, 4096, 1024, 4096);
}

// Round 2
// 333.051 us; speedup vs baseline: 1.2387x; 1.2387x over previous
//
#include <hip/hip_runtime.h>
#include <hip/hip_bf16.h>

typedef __attribute__((ext_vector_type(8))) short short8;
typedef __attribute__((ext_vector_type(4))) float f32x4;
using u16 = unsigned short;
typedef unsigned int u32;

__device__ __forceinline__ u16 f2bf(float f) {
    u32 u = __builtin_bit_cast(u32, f);
    u32 r = u + 0x7FFFu + ((u >> 16) & 1u);
    return (u16)(r >> 16);
}

__device__ __forceinline__ void async_load16(const void* g, void* l) {
    __builtin_amdgcn_global_load_lds(
        (const __attribute__((address_space(1))) void*)g,
        (__attribute__((address_space(3))) void*)l, 16, 0, 0);
}

// ---------------- weight transpose + f32->bf16 convert: w[K][N] -> wt[N][K] ----------------
__global__ __launch_bounds__(256) void convt_kernel(const float* __restrict__ w,
                                                    u16* __restrict__ wt, int K, int N) {
    __shared__ float tile[32][33];
    int bn = blockIdx.x * 32, bk = blockIdx.y * 32;
    int tx = threadIdx.x & 31, ty = threadIdx.x >> 5;  // 32 x 8
#pragma unroll
    for (int i = 0; i < 4; i++)
        tile[ty + i * 8][tx] = w[(size_t)(bk + ty + i * 8) * N + bn + tx];
    __syncthreads();
#pragma unroll
    for (int i = 0; i < 4; i++)
        wt[(size_t)(bn + ty + i * 8) * K + bk + tx] = f2bf(tile[tx][ty + i * 8]);
}

// ---------------- V transpose (bf16): qkv V-part [b][s][1024] -> vT[b*1024+col][2048] ----------------
__global__ __launch_bounds__(256) void vtrans_kernel(const u16* __restrict__ qkv,
                                                     u16* __restrict__ vT) {
    __shared__ u16 tile[32][33];
    int bs = blockIdx.x * 32;   // s tile
    int bc = blockIdx.y * 32;   // col tile
    int b  = blockIdx.z;
    int tx = threadIdx.x & 31, ty = threadIdx.x >> 5;  // 32 x 8
#pragma unroll
    for (int i = 0; i < 4; i++)
        tile[ty + i * 8][tx] = qkv[(size_t)(b * 2048 + bs + ty + i * 8) * 3072 + 2048 + bc + tx];
    __syncthreads();
#pragma unroll
    for (int i = 0; i < 4; i++)
        vT[(size_t)(b * 1024 + bc + ty + i * 8) * 2048 + bs + tx] = tile[tx][ty + i * 8];
}

// ---------------- LayerNorm (fp32 in, bf16 out), one block per row of 1024 ----------------
__global__ __launch_bounds__(256) void ln_kernel(const float* __restrict__ x,
                                                 const float* __restrict__ ga,
                                                 const float* __restrict__ gb,
                                                 u16* __restrict__ out) {
    int row = blockIdx.x;
    const float4* xr = (const float4*)(x + (size_t)row * 1024);
    float4 v = xr[threadIdx.x];
    float s  = v.x + v.y + v.z + v.w;
    float s2 = v.x * v.x + v.y * v.y + v.z * v.z + v.w * v.w;
#pragma unroll
    for (int off = 32; off; off >>= 1) {
        s  += __shfl_down(s, off);
        s2 += __shfl_down(s2, off);
    }
    __shared__ float rs[4], rs2[4];
    int wid = threadIdx.x >> 6, lane = threadIdx.x & 63;
    if (lane == 0) { rs[wid] = s; rs2[wid] = s2; }
    __syncthreads();
    float S  = rs[0] + rs[1] + rs[2] + rs[3];
    float S2 = rs2[0] + rs2[1] + rs2[2] + rs2[3];
    float mean = S * (1.0f / 1024.0f);
    float var  = fmaxf((S2 - 1024.0f * mean * mean) * (1.0f / 1023.0f), 0.0f);
    float scale = ga[0] / (sqrtf(var) + 1e-6f);
    float shift = gb[0] - mean * scale;
    u16 h0 = f2bf(v.x * scale + shift);
    u16 h1 = f2bf(v.y * scale + shift);
    u16 h2 = f2bf(v.z * scale + shift);
    u16 h3 = f2bf(v.w * scale + shift);
    uint2 pv;
    pv.x = (u32)h0 | ((u32)h1 << 16);
    pv.y = (u32)h2 | ((u32)h3 << 16);
    *(uint2*)(out + (size_t)row * 1024 + threadIdx.x * 4) = pv;
}

// ---------------- bf16 GEMM: C[M,N] = A[M,K] @ Bt[N,K]^T + bias (+relu/+resid) ----------------
template <int OUT_BF16, int RELU, int RESID>
__global__ __launch_bounds__(256) void gemm_bt(const u16* __restrict__ A,
                                               const u16* __restrict__ Bt,
                                               const float* __restrict__ bias,
                                               void* __restrict__ Cout,
                                               const float* __restrict__ resid,
                                               int M, int N, int K) {
    __shared__ u16 As[4096];  // [128][32]
    __shared__ u16 Bs[4096];  // [128][32]
    int tid = threadIdx.x, lane = tid & 63, wid = tid >> 6;
    int l15 = lane & 15, l4 = lane >> 4;
    int rowA0 = blockIdx.x * 128;
    int rowB0 = blockIdx.y * 128;
    int waveM = wid >> 1, waveN = wid & 1;

    int fl = tid * 8;
    int r0 = fl >> 5, c0 = fl & 31;
    const u16* gA0 = A + (size_t)(rowA0 + r0) * K + c0;
    const u16* gA1 = A + (size_t)(rowA0 + 64 + r0) * K + c0;
    const u16* gB0 = Bt + (size_t)(rowB0 + r0) * K + c0;
    const u16* gB1 = Bt + (size_t)(rowB0 + 64 + r0) * K + c0;
    u16* lA0 = As + wid * 512;
    u16* lA1 = As + 2048 + wid * 512;
    u16* lB0 = Bs + wid * 512;
    u16* lB1 = Bs + 2048 + wid * 512;

    f32x4 acc[4][4] = {};

    for (int k0 = 0; k0 < K; k0 += 32) {
        __syncthreads();
        async_load16(gA0 + k0, lA0);
        async_load16(gA1 + k0, lA1);
        async_load16(gB0 + k0, lB0);
        async_load16(gB1 + k0, lB1);
        __syncthreads();

        short8 af[4], bf[4];
#pragma unroll
        for (int m = 0; m < 4; m++)
            af[m] = *(const short8*)&As[(waveM * 64 + m * 16 + l15) * 32 + l4 * 8];
#pragma unroll
        for (int n = 0; n < 4; n++)
            bf[n] = *(const short8*)&Bs[(waveN * 64 + n * 16 + l15) * 32 + l4 * 8];
#pragma unroll
        for (int m = 0; m < 4; m++)
#pragma unroll
            for (int n = 0; n < 4; n++)
                acc[m][n] = __builtin_amdgcn_mfma_f32_16x16x32_bf16(af[m], bf[n], acc[m][n], 0, 0, 0);
    }

#pragma unroll
    for (int m = 0; m < 4; m++) {
        int row = rowA0 + waveM * 64 + m * 16 + l4 * 4;
#pragma unroll
        for (int n = 0; n < 4; n++) {
            int col = rowB0 + waveN * 64 + n * 16 + l15;
            float bc = bias[col];
#pragma unroll
            for (int j = 0; j < 4; j++) {
                float v = acc[m][n][j] + bc;
                if (RELU) v = fmaxf(v, 0.0f);
                if (RESID) v += resid[(size_t)(row + j) * N + col];
                if (OUT_BF16)
                    ((u16*)Cout)[(size_t)(row + j) * N + col] = f2bf(v);
                else
                    ((float*)Cout)[(size_t)(row + j) * N + col] = v;
            }
        }
    }
}

// ---------------- flash attention v2: pre-transposed V, deferred max, lazy row-sum ----------------
__global__ __launch_bounds__(256) void attn_kernel(const u16* __restrict__ qkv,
                                                   const u16* __restrict__ vT,
                                                   const int* __restrict__ mask,
                                                   u16* __restrict__ ctx) {
    const int S = 2048;
    const float SCALE = 0.125f;  // 1/sqrt(64)
    int qt = blockIdx.x;
    int bh = blockIdx.y;
    int b = bh >> 4, h = bh & 15;
    int tid = threadIdx.x;
    int wid = tid >> 6, lane = tid & 63;
    int l15 = lane & 15, l4 = lane >> 4;

    __shared__ u16 Ks[64][72];       // K rows (s-local) x d
    __shared__ u16 Vs[64][72];       // V^T rows (d-local) x s
    __shared__ u16 Plds[4][16][72];  // per-wave P relayout
    __shared__ int mflag;

    if (tid == 0) mflag = 1;
    __syncthreads();
    {
        const int* mrow = mask + b * S;
        int ok = 1;
#pragma unroll
        for (int i = 0; i < 8; i++) ok &= (mrow[tid * 8 + i] != 0);
        if (!ok) mflag = 0;
    }

    int qrow0 = qt * 64 + wid * 16;
    const u16* qb = qkv + (size_t)(b * S + qrow0) * 3072 + h * 64;
    short8 qf0 = *(const short8*)(qb + (size_t)l15 * 3072 + l4 * 8);
    short8 qf1 = *(const short8*)(qb + (size_t)l15 * 3072 + 32 + l4 * 8);

    f32x4 o[4] = {};
    float m_i[4], lp[4];
#pragma unroll
    for (int j = 0; j < 4; j++) { m_i[j] = -1e30f; lp[j] = 0.0f; }
    __syncthreads();
    const int allones = mflag;
    const int* mrow = mask + b * S;

    for (int kt = 0; kt < 32; ++kt) {
        __syncthreads();
        {
            int srow = tid >> 3, c8 = (tid & 7) * 8;
#pragma unroll
            for (int p = 0; p < 2; p++) {
                int r = p * 32 + srow;
                *(short8*)&Ks[r][c8] =
                    *(const short8*)(qkv + (size_t)(b * S + kt * 64 + r) * 3072 + 1024 + h * 64 + c8);
                *(short8*)&Vs[r][c8] =
                    *(const short8*)(vT + (size_t)(bh * 64 + r) * 2048 + kt * 64 + c8);
            }
        }
        __syncthreads();

        // QK^T: sc[kc][j] = scores, row = l4*4+j (q-local), col = kc*16+l15 (s-local)
        float sc[4][4];
#pragma unroll
        for (int kc = 0; kc < 4; kc++) {
            short8 kf0 = *(const short8*)&Ks[kc * 16 + l15][l4 * 8];
            short8 kf1 = *(const short8*)&Ks[kc * 16 + l15][32 + l4 * 8];
            f32x4 a = {};
            a = __builtin_amdgcn_mfma_f32_16x16x32_bf16(qf0, kf0, a, 0, 0, 0);
            a = __builtin_amdgcn_mfma_f32_16x16x32_bf16(qf1, kf1, a, 0, 0, 0);
            if (allones) {
#pragma unroll
                for (int j = 0; j < 4; j++) sc[kc][j] = a[j] * SCALE;
            } else {
                int mk = mrow[kt * 64 + kc * 16 + l15];
#pragma unroll
                for (int j = 0; j < 4; j++) sc[kc][j] = mk ? a[j] * SCALE : -1e9f;
            }
        }

        // deferred-max online softmax (THR=8): common path has no shuffles, no rescale
        float lm[4];
#pragma unroll
        for (int j = 0; j < 4; j++)
            lm[j] = fmaxf(fmaxf(sc[0][j], sc[1][j]), fmaxf(sc[2][j], sc[3][j]));
        bool ok2 = (lm[0] <= m_i[0] + 8.0f) && (lm[1] <= m_i[1] + 8.0f) &&
                   (lm[2] <= m_i[2] + 8.0f) && (lm[3] <= m_i[3] + 8.0f);
        if (!__all(ok2)) {
#pragma unroll
            for (int j = 0; j < 4; j++) {
                float t = lm[j];
#pragma unroll
                for (int mm = 8; mm >= 1; mm >>= 1) t = fmaxf(t, __shfl_xor(t, mm, 16));
                float newm = fmaxf(m_i[j], t);
                float r = __expf(m_i[j] - newm);
                lp[j] *= r;
#pragma unroll
                for (int dc = 0; dc < 4; dc++) o[dc][j] *= r;
                m_i[j] = newm;
            }
        }
#pragma unroll
        for (int j = 0; j < 4; j++) {
#pragma unroll
            for (int kc = 0; kc < 4; kc++) {
                float p = __expf(sc[kc][j] - m_i[j]);
                lp[j] += p;
                Plds[wid][l4 * 4 + j][kc * 16 + l15] = f2bf(p);
            }
        }

        short8 pa0 = *(const short8*)&Plds[wid][l15][l4 * 8];
        short8 pa1 = *(const short8*)&Plds[wid][l15][32 + l4 * 8];
#pragma unroll
        for (int dc = 0; dc < 4; dc++) {
            short8 vf0 = *(const short8*)&Vs[dc * 16 + l15][l4 * 8];
            short8 vf1 = *(const short8*)&Vs[dc * 16 + l15][32 + l4 * 8];
            o[dc] = __builtin_amdgcn_mfma_f32_16x16x32_bf16(pa0, vf0, o[dc], 0, 0, 0);
            o[dc] = __builtin_amdgcn_mfma_f32_16x16x32_bf16(pa1, vf1, o[dc], 0, 0, 0);
        }
    }

    // final row-sum: reduce per-thread partials across the 16 column-lanes
#pragma unroll
    for (int j = 0; j < 4; j++) {
        float s = lp[j];
#pragma unroll
        for (int mm = 8; mm >= 1; mm >>= 1) s += __shfl_xor(s, mm, 16);
        float inv = 1.0f / s;
        int row = qrow0 + l4 * 4 + j;
        size_t base = (size_t)(b * S + row) * 1024 + h * 64;
#pragma unroll
        for (int dc = 0; dc < 4; dc++)
            ctx[base + dc * 16 + l15] = f2bf(o[dc][j] * inv);
    }
}

// ---------------- launcher ----------------
extern "C" void kernel_launch(void* const* d_in, const int* in_sizes, int n_in,
                              void* d_out, int out_size, void* d_ws, size_t ws_size,
                              hipStream_t stream) {
    const float* x    = (const float*)d_in[0];
    const int*   mask = (const int*)d_in[1];
    const float* wq   = (const float*)d_in[2];
    const float* wk   = (const float*)d_in[4];
    const float* wv   = (const float*)d_in[6];
    const float* wo   = (const float*)d_in[8];
    const float* bo   = (const float*)d_in[9];
    const float* w1   = (const float*)d_in[10];
    const float* b1   = (const float*)d_in[11];
    const float* w2   = (const float*)d_in[12];
    const float* b2   = (const float*)d_in[13];
    const float* bq   = (const float*)d_in[3];
    const float* bk   = (const float*)d_in[5];
    const float* bv   = (const float*)d_in[7];
    const float* ln1a = (const float*)d_in[14];
    const float* ln1b = (const float*)d_in[15];
    const float* ln2a = (const float*)d_in[16];
    const float* ln2b = (const float*)d_in[17];
    float* out = (float*)d_out;

    char* ws = (char*)d_ws;
    u16*   wqkvt = (u16*)(ws + 0);                  //  6 MB
    u16*   wot   = (u16*)(ws + 6291456);            //  2 MB
    u16*   w1t   = (u16*)(ws + 8388608);            //  8 MB
    u16*   w2t   = (u16*)(ws + 16777216);           //  8 MB
    float* bqkv  = (float*)(ws + 25165824);         // 12 KB
    char*  regA  = ws + 26214400;
    u16*   xn1   = (u16*)(regA + 0);                //  8 MB
    u16*   vT    = (u16*)(regA + 0);                //  8 MB (aliases xn1; live after QKV gemm)
    u16*   qkv   = (u16*)(regA + 8388608);          // 24 MB
    u16*   ctx   = (u16*)(regA + 33554432);         //  8 MB
    float* x1    = (float*)(ws + 68157440);         // 16 MB
    u16*   xn2   = (u16*)(regA + 0);                // reuse (vT dead after attn)
    u16*   ff1   = (u16*)(regA + 8388608);          // reuse

    dim3 blk(256);

    convt_kernel<<<dim3(32, 32), blk, 0, stream>>>(wq, wqkvt, 1024, 1024);
    convt_kernel<<<dim3(32, 32), blk, 0, stream>>>(wk, wqkvt + 1024 * 1024, 1024, 1024);
    convt_kernel<<<dim3(32, 32), blk, 0, stream>>>(wv, wqkvt + 2048 * 1024, 1024, 1024);
    convt_kernel<<<dim3(32, 32), blk, 0, stream>>>(wo, wot, 1024, 1024);
    convt_kernel<<<dim3(128, 32), blk, 0, stream>>>(w1, w1t, 1024, 4096);
    convt_kernel<<<dim3(32, 128), blk, 0, stream>>>(w2, w2t, 4096, 1024);
    hipMemcpyAsync(bqkv, bq, 4096, hipMemcpyDeviceToDevice, stream);
    hipMemcpyAsync(bqkv + 1024, bk, 4096, hipMemcpyDeviceToDevice, stream);
    hipMemcpyAsync(bqkv + 2048, bv, 4096, hipMemcpyDeviceToDevice, stream);

    ln_kernel<<<dim3(4096), blk, 0, stream>>>(x, ln1a, ln1b, xn1);
    gemm_bt<1, 0, 0><<<dim3(32, 24), blk, 0, stream>>>(xn1, wqkvt, bqkv, qkv, nullptr, 4096, 3072, 1024);
    vtrans_kernel<<<dim3(64, 32, 2), blk, 0, stream>>>(qkv, vT);
    attn_kernel<<<dim3(32, 32), blk, 0, stream>>>(qkv, vT, mask, ctx);
    gemm_bt<0, 0, 1><<<dim3(32, 8), blk, 0, stream>>>(ctx, wot, bo, x1, x, 4096, 1024, 1024);

    ln_kernel<<<dim3(4096), blk, 0, stream>>>(x1, ln2a, ln2b, xn2);
    gemm_bt<1, 1, 0><<<dim3(32, 32), blk, 0, stream>>>(xn2, w1t, b1, ff1, nullptr, 4096, 4096, 1024);
    gemm_bt<0, 0, 1><<<dim3(32, 8), blk, 0, stream>>>(ff1, w2t, b2, out, x1, 4096, 1024, 4096);
}

// Round 3
// 293.537 us; speedup vs baseline: 1.4055x; 1.1346x over previous
//
#include <hip/hip_runtime.h>
#include <hip/hip_bf16.h>

typedef __attribute__((ext_vector_type(8))) short short8;
typedef __attribute__((ext_vector_type(4))) float f32x4;
using u16 = unsigned short;
typedef unsigned int u32;

__device__ __forceinline__ u16 f2bf(float f) {
    u32 u = __builtin_bit_cast(u32, f);
    u32 r = u + 0x7FFFu + ((u >> 16) & 1u);
    return (u16)(r >> 16);
}

__device__ __forceinline__ void async_load16(const void* g, void* l) {
    __builtin_amdgcn_global_load_lds(
        (const __attribute__((address_space(1))) void*)g,
        (__attribute__((address_space(3))) void*)l, 16, 0, 0);
}

// ---------------- weight transpose + f32->bf16 convert: w[K][N] -> wt[N][K] ----------------
__global__ __launch_bounds__(256) void convt_kernel(const float* __restrict__ w,
                                                    u16* __restrict__ wt, int K, int N) {
    __shared__ float tile[32][33];
    int bn = blockIdx.x * 32, bk = blockIdx.y * 32;
    int tx = threadIdx.x & 31, ty = threadIdx.x >> 5;  // 32 x 8
#pragma unroll
    for (int i = 0; i < 4; i++)
        tile[ty + i * 8][tx] = w[(size_t)(bk + ty + i * 8) * N + bn + tx];
    __syncthreads();
#pragma unroll
    for (int i = 0; i < 4; i++)
        wt[(size_t)(bn + ty + i * 8) * K + bk + tx] = f2bf(tile[tx][ty + i * 8]);
}

// ---------------- V transpose (bf16): qkv V-part [b][s][1024] -> vT[b*1024+col][2048] ----------------
__global__ __launch_bounds__(256) void vtrans_kernel(const u16* __restrict__ qkv,
                                                     u16* __restrict__ vT) {
    __shared__ u16 tile[32][33];
    int bs = blockIdx.x * 32;   // s tile
    int bc = blockIdx.y * 32;   // col tile
    int b  = blockIdx.z;
    int tx = threadIdx.x & 31, ty = threadIdx.x >> 5;  // 32 x 8
#pragma unroll
    for (int i = 0; i < 4; i++)
        tile[ty + i * 8][tx] = qkv[(size_t)(b * 2048 + bs + ty + i * 8) * 3072 + 2048 + bc + tx];
    __syncthreads();
#pragma unroll
    for (int i = 0; i < 4; i++)
        vT[(size_t)(b * 1024 + bc + ty + i * 8) * 2048 + bs + tx] = tile[tx][ty + i * 8];
}

// ---------------- LayerNorm (fp32 in, bf16 out), one block per row of 1024 ----------------
__global__ __launch_bounds__(256) void ln_kernel(const float* __restrict__ x,
                                                 const float* __restrict__ ga,
                                                 const float* __restrict__ gb,
                                                 u16* __restrict__ out) {
    int row = blockIdx.x;
    const float4* xr = (const float4*)(x + (size_t)row * 1024);
    float4 v = xr[threadIdx.x];
    float s  = v.x + v.y + v.z + v.w;
    float s2 = v.x * v.x + v.y * v.y + v.z * v.z + v.w * v.w;
#pragma unroll
    for (int off = 32; off; off >>= 1) {
        s  += __shfl_down(s, off);
        s2 += __shfl_down(s2, off);
    }
    __shared__ float rs[4], rs2[4];
    int wid = threadIdx.x >> 6, lane = threadIdx.x & 63;
    if (lane == 0) { rs[wid] = s; rs2[wid] = s2; }
    __syncthreads();
    float S  = rs[0] + rs[1] + rs[2] + rs[3];
    float S2 = rs2[0] + rs2[1] + rs2[2] + rs2[3];
    float mean = S * (1.0f / 1024.0f);
    float var  = fmaxf((S2 - 1024.0f * mean * mean) * (1.0f / 1023.0f), 0.0f);
    float scale = ga[0] / (sqrtf(var) + 1e-6f);
    float shift = gb[0] - mean * scale;
    u16 h0 = f2bf(v.x * scale + shift);
    u16 h1 = f2bf(v.y * scale + shift);
    u16 h2 = f2bf(v.z * scale + shift);
    u16 h3 = f2bf(v.w * scale + shift);
    uint2 pv;
    pv.x = (u32)h0 | ((u32)h1 << 16);
    pv.y = (u32)h2 | ((u32)h3 << 16);
    *(uint2*)(out + (size_t)row * 1024 + threadIdx.x * 4) = pv;
}

// ---------------- bias concat: [bq|bk|bv] -> bqkv ----------------
__global__ __launch_bounds__(256) void bias3_kernel(const float* __restrict__ a,
                                                    const float* __restrict__ b,
                                                    const float* __restrict__ c,
                                                    float* __restrict__ d) {
    int i = blockIdx.x * 256 + threadIdx.x;  // 3072 total
    float v = (i < 1024) ? a[i] : ((i < 2048) ? b[i - 1024] : c[i - 2048]);
    d[i] = v;
}

// ---------------- fused reduce: dst += p + bias[col] + resid (N=1024 row width) ----------------
__global__ __launch_bounds__(256) void addbias_kernel(float* __restrict__ dst,
                                                      const float* __restrict__ p,
                                                      const float* __restrict__ bias,
                                                      const float* __restrict__ resid) {
    int i4 = blockIdx.x * 256 + threadIdx.x;  // float4 index, 1M total
    float4 d  = ((const float4*)dst)[i4];
    float4 pp = ((const float4*)p)[i4];
    float4 rr = ((const float4*)resid)[i4];
    float4 bb = *(const float4*)(bias + ((i4 * 4) & 1023));
    d.x += pp.x + bb.x + rr.x;
    d.y += pp.y + bb.y + rr.y;
    d.z += pp.z + bb.z + rr.z;
    d.w += pp.w + bb.w + rr.w;
    ((float4*)dst)[i4] = d;
}

// ---------------- bf16 GEMM, 2-phase double-buffered, optional split-K via gridDim.z ----------------
// MODE: 0 = f32 out + bias, 1 = bf16 out + bias, 2 = f32 partial (no bias/resid)
template <int MODE, int RELU, int RESID>
__global__ __launch_bounds__(256) void gemm_bt(const u16* __restrict__ A,
                                               const u16* __restrict__ Bt,
                                               const float* __restrict__ bias,
                                               void* __restrict__ C0,
                                               void* __restrict__ C1,
                                               const float* __restrict__ resid,
                                               int M, int N, int K, int kLen) {
    __shared__ u16 As[8192];  // 2 x [128][32]
    __shared__ u16 Bs[8192];
    int tid = threadIdx.x, lane = tid & 63, wid = tid >> 6;
    int l15 = lane & 15, l4 = lane >> 4;
    int rowA0 = blockIdx.x * 128;
    int rowB0 = blockIdx.y * 128;
    int kOff = blockIdx.z * kLen;
    void* Cout = blockIdx.z ? C1 : C0;
    int waveM = wid >> 1, waveN = wid & 1;

    int fl = tid * 8;
    int r0 = fl >> 5, c0 = fl & 31;
    const u16* gA0 = A + (size_t)(rowA0 + r0) * K + c0 + kOff;
    const u16* gA1 = A + (size_t)(rowA0 + 64 + r0) * K + c0 + kOff;
    const u16* gB0 = Bt + (size_t)(rowB0 + r0) * K + c0 + kOff;
    const u16* gB1 = Bt + (size_t)(rowB0 + 64 + r0) * K + c0 + kOff;

    f32x4 acc[4][4] = {};
    const int nIter = kLen >> 5;

    // prologue: stage tile 0 into buf 0
    async_load16(gA0, As + wid * 512);
    async_load16(gA1, As + 2048 + wid * 512);
    async_load16(gB0, Bs + wid * 512);
    async_load16(gB1, Bs + 2048 + wid * 512);

    int cur = 0, kb = 32;
    for (int it = 0; it < nIter; ++it) {
        asm volatile("s_waitcnt vmcnt(0)" ::: "memory");
        __builtin_amdgcn_s_barrier();
        if (it + 1 < nIter) {  // prefetch next tile into the other buffer
            u16* a = As + (cur ^ 1) * 4096;
            u16* bb = Bs + (cur ^ 1) * 4096;
            async_load16(gA0 + kb, a + wid * 512);
            async_load16(gA1 + kb, a + 2048 + wid * 512);
            async_load16(gB0 + kb, bb + wid * 512);
            async_load16(gB1 + kb, bb + 2048 + wid * 512);
        }
        __builtin_amdgcn_sched_barrier(0);  // keep prefetch issued before compute

        const u16* a = As + cur * 4096;
        const u16* bb = Bs + cur * 4096;
        short8 af[4], bf[4];
#pragma unroll
        for (int m = 0; m < 4; m++)
            af[m] = *(const short8*)&a[(waveM * 64 + m * 16 + l15) * 32 + l4 * 8];
#pragma unroll
        for (int n = 0; n < 4; n++)
            bf[n] = *(const short8*)&bb[(waveN * 64 + n * 16 + l15) * 32 + l4 * 8];
#pragma unroll
        for (int m = 0; m < 4; m++)
#pragma unroll
            for (int n = 0; n < 4; n++)
                acc[m][n] = __builtin_amdgcn_mfma_f32_16x16x32_bf16(af[m], bf[n], acc[m][n], 0, 0, 0);

        __builtin_amdgcn_s_barrier();
        cur ^= 1;
        kb += 32;
    }

#pragma unroll
    for (int m = 0; m < 4; m++) {
        int row = rowA0 + waveM * 64 + m * 16 + l4 * 4;
#pragma unroll
        for (int n = 0; n < 4; n++) {
            int col = rowB0 + waveN * 64 + n * 16 + l15;
            float bc = (MODE == 2) ? 0.0f : bias[col];
#pragma unroll
            for (int j = 0; j < 4; j++) {
                float v = acc[m][n][j] + bc;
                if (RELU) v = fmaxf(v, 0.0f);
                if (RESID) v += resid[(size_t)(row + j) * N + col];
                if (MODE == 1)
                    ((u16*)Cout)[(size_t)(row + j) * N + col] = f2bf(v);
                else
                    ((float*)Cout)[(size_t)(row + j) * N + col] = v;
            }
        }
    }
}

// ---------------- flash attention v3: T14 async-stage, deferred max, lazy row-sum ----------------
__global__ __launch_bounds__(256) void attn_kernel(const u16* __restrict__ qkv,
                                                   const u16* __restrict__ vT,
                                                   const int* __restrict__ mask,
                                                   u16* __restrict__ ctx) {
    const int S = 2048;
    const float SCALE = 0.125f;  // 1/sqrt(64)
    int qt = blockIdx.x;
    int bh = blockIdx.y;
    int b = bh >> 4, h = bh & 15;
    int tid = threadIdx.x;
    int wid = tid >> 6, lane = tid & 63;
    int l15 = lane & 15, l4 = lane >> 4;

    __shared__ u16 Ks[64][72];
    __shared__ u16 Vs[64][72];
    __shared__ u16 Plds[4][16][72];
    __shared__ int mflag;

    if (tid == 0) mflag = 1;
    __syncthreads();
    {
        const int* mrow = mask + b * S;
        int ok = 1;
#pragma unroll
        for (int i = 0; i < 8; i++) ok &= (mrow[tid * 8 + i] != 0);
        if (!ok) mflag = 0;
    }

    int qrow0 = qt * 64 + wid * 16;
    const u16* qb = qkv + (size_t)(b * S + qrow0) * 3072 + h * 64;
    short8 qf0 = *(const short8*)(qb + (size_t)l15 * 3072 + l4 * 8);
    short8 qf1 = *(const short8*)(qb + (size_t)l15 * 3072 + 32 + l4 * 8);

    f32x4 o[4] = {};
    float m_i[4], lp[4];
#pragma unroll
    for (int j = 0; j < 4; j++) { m_i[j] = -1e30f; lp[j] = 0.0f; }
    __syncthreads();
    const int allones = mflag;
    const int* mrow = mask + b * S;

    // per-thread staging coords: 2 rows x 16B of K and V tiles
    int srow = tid >> 3, c8 = (tid & 7) * 8;
    short8 kreg[2], vreg[2];
#pragma unroll
    for (int p = 0; p < 2; p++) {
        int r = p * 32 + srow;
        kreg[p] = *(const short8*)(qkv + (size_t)(b * S + r) * 3072 + 1024 + h * 64 + c8);
        vreg[p] = *(const short8*)(vT + (size_t)(bh * 64 + r) * 2048 + c8);
    }

    for (int kt = 0; kt < 32; ++kt) {
        __builtin_amdgcn_s_barrier();  // all waves done reading previous tile
#pragma unroll
        for (int p = 0; p < 2; p++) {
            int r = p * 32 + srow;
            *(short8*)&Ks[r][c8] = kreg[p];
            *(short8*)&Vs[r][c8] = vreg[p];
        }
        if (kt + 1 < 32) {  // prefetch next tile into regs; latency hides under compute
#pragma unroll
            for (int p = 0; p < 2; p++) {
                int r = p * 32 + srow;
                kreg[p] = *(const short8*)(qkv + (size_t)(b * S + (kt + 1) * 64 + r) * 3072 + 1024 + h * 64 + c8);
                vreg[p] = *(const short8*)(vT + (size_t)(bh * 64 + r) * 2048 + (kt + 1) * 64 + c8);
            }
        }
        asm volatile("s_waitcnt lgkmcnt(0)" ::: "memory");
        __builtin_amdgcn_s_barrier();

        // QK^T
        float sc[4][4];
#pragma unroll
        for (int kc = 0; kc < 4; kc++) {
            short8 kf0 = *(const short8*)&Ks[kc * 16 + l15][l4 * 8];
            short8 kf1 = *(const short8*)&Ks[kc * 16 + l15][32 + l4 * 8];
            f32x4 a = {};
            a = __builtin_amdgcn_mfma_f32_16x16x32_bf16(qf0, kf0, a, 0, 0, 0);
            a = __builtin_amdgcn_mfma_f32_16x16x32_bf16(qf1, kf1, a, 0, 0, 0);
            if (allones) {
#pragma unroll
                for (int j = 0; j < 4; j++) sc[kc][j] = a[j] * SCALE;
            } else {
                int mk = mrow[kt * 64 + kc * 16 + l15];
#pragma unroll
                for (int j = 0; j < 4; j++) sc[kc][j] = mk ? a[j] * SCALE : -1e9f;
            }
        }

        // deferred-max online softmax (THR=8)
        float lm[4];
#pragma unroll
        for (int j = 0; j < 4; j++)
            lm[j] = fmaxf(fmaxf(sc[0][j], sc[1][j]), fmaxf(sc[2][j], sc[3][j]));
        bool ok2 = (lm[0] <= m_i[0] + 8.0f) && (lm[1] <= m_i[1] + 8.0f) &&
                   (lm[2] <= m_i[2] + 8.0f) && (lm[3] <= m_i[3] + 8.0f);
        if (!__all(ok2)) {
#pragma unroll
            for (int j = 0; j < 4; j++) {
                float t = lm[j];
#pragma unroll
                for (int mm = 8; mm >= 1; mm >>= 1) t = fmaxf(t, __shfl_xor(t, mm, 16));
                float newm = fmaxf(m_i[j], t);
                float r = __expf(m_i[j] - newm);
                lp[j] *= r;
#pragma unroll
                for (int dc = 0; dc < 4; dc++) o[dc][j] *= r;
                m_i[j] = newm;
            }
        }
#pragma unroll
        for (int j = 0; j < 4; j++) {
#pragma unroll
            for (int kc = 0; kc < 4; kc++) {
                float p = __expf(sc[kc][j] - m_i[j]);
                lp[j] += p;
                Plds[wid][l4 * 4 + j][kc * 16 + l15] = f2bf(p);
            }
        }

        short8 pa0 = *(const short8*)&Plds[wid][l15][l4 * 8];
        short8 pa1 = *(const short8*)&Plds[wid][l15][32 + l4 * 8];
#pragma unroll
        for (int dc = 0; dc < 4; dc++) {
            short8 vf0 = *(const short8*)&Vs[dc * 16 + l15][l4 * 8];
            short8 vf1 = *(const short8*)&Vs[dc * 16 + l15][32 + l4 * 8];
            o[dc] = __builtin_amdgcn_mfma_f32_16x16x32_bf16(pa0, vf0, o[dc], 0, 0, 0);
            o[dc] = __builtin_amdgcn_mfma_f32_16x16x32_bf16(pa1, vf1, o[dc], 0, 0, 0);
        }
    }

#pragma unroll
    for (int j = 0; j < 4; j++) {
        float s = lp[j];
#pragma unroll
        for (int mm = 8; mm >= 1; mm >>= 1) s += __shfl_xor(s, mm, 16);
        float inv = 1.0f / s;
        int row = qrow0 + l4 * 4 + j;
        size_t base = (size_t)(b * S + row) * 1024 + h * 64;
#pragma unroll
        for (int dc = 0; dc < 4; dc++)
            ctx[base + dc * 16 + l15] = f2bf(o[dc][j] * inv);
    }
}

// ---------------- launcher ----------------
extern "C" void kernel_launch(void* const* d_in, const int* in_sizes, int n_in,
                              void* d_out, int out_size, void* d_ws, size_t ws_size,
                              hipStream_t stream) {
    const float* x    = (const float*)d_in[0];
    const int*   mask = (const int*)d_in[1];
    const float* wq   = (const float*)d_in[2];
    const float* bq   = (const float*)d_in[3];
    const float* wk   = (const float*)d_in[4];
    const float* bk   = (const float*)d_in[5];
    const float* wv   = (const float*)d_in[6];
    const float* bv   = (const float*)d_in[7];
    const float* wo   = (const float*)d_in[8];
    const float* bo   = (const float*)d_in[9];
    const float* w1   = (const float*)d_in[10];
    const float* b1   = (const float*)d_in[11];
    const float* w2   = (const float*)d_in[12];
    const float* b2   = (const float*)d_in[13];
    const float* ln1a = (const float*)d_in[14];
    const float* ln1b = (const float*)d_in[15];
    const float* ln2a = (const float*)d_in[16];
    const float* ln2b = (const float*)d_in[17];
    float* out = (float*)d_out;

    char* ws = (char*)d_ws;
    u16*   wqkvt = (u16*)(ws + 0);            //  6 MB  (dead after QKV gemm)
    u16*   wot   = (u16*)(ws + 6291456);      //  2 MB  (dead after WO gemm)
    u16*   w1t   = (u16*)(ws + 8388608);      //  8 MB  (dead after FFN1)
    u16*   w2t   = (u16*)(ws + 16777216);     //  8 MB
    float* bqkv  = (float*)(ws + 25165824);   // 12 KB
    char*  regA  = ws + 26214400;             // 41.9 MB scratch region
    u16*   xn1   = (u16*)(regA + 0);          //  8 MB
    u16*   vT    = (u16*)(regA + 0);          //  8 MB (aliases xn1)
    u16*   qkv   = (u16*)(regA + 8388608);    // 24 MB
    u16*   ctx   = (u16*)(regA + 33554432);   //  8 MB
    float* p0wo  = (float*)(regA + 0);        // 16 MB (vT+qkv dead by WO time)
    float* x1    = (float*)(ws + 68157440);   // 16 MB
    u16*   xn2   = (u16*)(regA + 0);          //  8 MB (p0wo dead after reduce)
    u16*   ff1   = (u16*)(regA + 8388608);    // 32 MB
    float* p0f2  = (float*)(ws + 0);          // 16 MB (wqkvt/wot/w1t dead by FFN2 time)

    dim3 blk(256);

    convt_kernel<<<dim3(32, 32), blk, 0, stream>>>(wq, wqkvt, 1024, 1024);
    convt_kernel<<<dim3(32, 32), blk, 0, stream>>>(wk, wqkvt + 1024 * 1024, 1024, 1024);
    convt_kernel<<<dim3(32, 32), blk, 0, stream>>>(wv, wqkvt + 2048 * 1024, 1024, 1024);
    convt_kernel<<<dim3(32, 32), blk, 0, stream>>>(wo, wot, 1024, 1024);
    convt_kernel<<<dim3(128, 32), blk, 0, stream>>>(w1, w1t, 1024, 4096);
    convt_kernel<<<dim3(32, 128), blk, 0, stream>>>(w2, w2t, 4096, 1024);
    bias3_kernel<<<dim3(12), blk, 0, stream>>>(bq, bk, bv, bqkv);

    // LN1 -> QKV -> attn -> WO (split-K=2) + reduce(+bo+x)
    ln_kernel<<<dim3(4096), blk, 0, stream>>>(x, ln1a, ln1b, xn1);
    gemm_bt<1, 0, 0><<<dim3(32, 24, 1), blk, 0, stream>>>(xn1, wqkvt, bqkv, qkv, qkv, nullptr,
                                                          4096, 3072, 1024, 1024);
    vtrans_kernel<<<dim3(64, 32, 2), blk, 0, stream>>>(qkv, vT);
    attn_kernel<<<dim3(32, 32), blk, 0, stream>>>(qkv, vT, mask, ctx);
    gemm_bt<2, 0, 0><<<dim3(32, 8, 2), blk, 0, stream>>>(ctx, wot, nullptr, p0wo, x1, nullptr,
                                                         4096, 1024, 1024, 512);
    addbias_kernel<<<dim3(4096), blk, 0, stream>>>(x1, p0wo, bo, x);

    // LN2 -> FFN1(relu) -> FFN2 (split-K=2) + reduce(+b2+x1)
    ln_kernel<<<dim3(4096), blk, 0, stream>>>(x1, ln2a, ln2b, xn2);
    gemm_bt<1, 1, 0><<<dim3(32, 32, 1), blk, 0, stream>>>(xn2, w1t, b1, ff1, ff1, nullptr,
                                                          4096, 4096, 1024, 1024);
    gemm_bt<2, 0, 0><<<dim3(32, 8, 2), blk, 0, stream>>>(ff1, w2t, nullptr, p0f2, out, nullptr,
                                                         4096, 1024, 4096, 2048);
    addbias_kernel<<<dim3(4096), blk, 0, stream>>>(out, p0f2, b2, x1);
}

// Round 5
// 277.043 us; speedup vs baseline: 1.4892x; 1.0595x over previous
//
#include <hip/hip_runtime.h>
#include <hip/hip_bf16.h>

typedef __attribute__((ext_vector_type(8))) short short8;
typedef __attribute__((ext_vector_type(4))) float f32x4;
typedef __attribute__((ext_vector_type(4))) unsigned int u32x4;
using u16 = unsigned short;
typedef unsigned int u32;

__device__ __forceinline__ u16 f2bf(float f) {
    u32 u = __builtin_bit_cast(u32, f);
    u32 r = u + 0x7FFFu + ((u >> 16) & 1u);
    return (u16)(r >> 16);
}

__device__ __forceinline__ float exp2fast(float x) {
    return __builtin_amdgcn_exp2f(x);  // v_exp_f32
}

__device__ __forceinline__ u32 cvtpk(float lo, float hi) {
    u32 r;
    asm("v_cvt_pk_bf16_f32 %0, %1, %2" : "=v"(r) : "v"(lo), "v"(hi));
    return r;
}

__device__ __forceinline__ void async_load16(const void* g, void* l) {
    __builtin_amdgcn_global_load_lds(
        (const __attribute__((address_space(1))) void*)g,
        (__attribute__((address_space(3))) void*)l, 16, 0, 0);
}

// ---------------- weight transpose + f32->bf16 convert: w[K][N] -> wt[N][K] ----------------
__global__ __launch_bounds__(256) void convt_kernel(const float* __restrict__ w,
                                                    u16* __restrict__ wt, int K, int N) {
    __shared__ float tile[32][33];
    int bn = blockIdx.x * 32, bk = blockIdx.y * 32;
    int tx = threadIdx.x & 31, ty = threadIdx.x >> 5;
#pragma unroll
    for (int i = 0; i < 4; i++)
        tile[ty + i * 8][tx] = w[(size_t)(bk + ty + i * 8) * N + bn + tx];
    __syncthreads();
#pragma unroll
    for (int i = 0; i < 4; i++)
        wt[(size_t)(bn + ty + i * 8) * K + bk + tx] = f2bf(tile[tx][ty + i * 8]);
}

// 4 square 1024x1024 transposes in one launch (blockIdx.z selects weight)
__global__ __launch_bounds__(256) void convt4_kernel(const float* __restrict__ wa,
                                                     const float* __restrict__ wb,
                                                     const float* __restrict__ wc,
                                                     const float* __restrict__ wd,
                                                     u16* __restrict__ da,
                                                     u16* __restrict__ db,
                                                     u16* __restrict__ dc,
                                                     u16* __restrict__ dd) {
    __shared__ float tile[32][33];
    int z = blockIdx.z;
    const float* w = (z == 0) ? wa : (z == 1) ? wb : (z == 2) ? wc : wd;
    u16* wt = (z == 0) ? da : (z == 1) ? db : (z == 2) ? dc : dd;
    int bn = blockIdx.x * 32, bk = blockIdx.y * 32;
    int tx = threadIdx.x & 31, ty = threadIdx.x >> 5;
#pragma unroll
    for (int i = 0; i < 4; i++)
        tile[ty + i * 8][tx] = w[(size_t)(bk + ty + i * 8) * 1024 + bn + tx];
    __syncthreads();
#pragma unroll
    for (int i = 0; i < 4; i++)
        wt[(size_t)(bn + ty + i * 8) * 1024 + bk + tx] = f2bf(tile[tx][ty + i * 8]);
}

// ---------------- V transpose (bf16): qkv V-part [b][s][1024] -> vT[b*1024+col][2048] ----------------
__global__ __launch_bounds__(256) void vtrans_kernel(const u16* __restrict__ qkv,
                                                     u16* __restrict__ vT) {
    __shared__ u16 tile[32][33];
    int bs = blockIdx.x * 32;
    int bc = blockIdx.y * 32;
    int b  = blockIdx.z;
    int tx = threadIdx.x & 31, ty = threadIdx.x >> 5;
#pragma unroll
    for (int i = 0; i < 4; i++)
        tile[ty + i * 8][tx] = qkv[(size_t)(b * 2048 + bs + ty + i * 8) * 3072 + 2048 + bc + tx];
    __syncthreads();
#pragma unroll
    for (int i = 0; i < 4; i++)
        vT[(size_t)(b * 1024 + bc + ty + i * 8) * 2048 + bs + tx] = tile[tx][ty + i * 8];
}

// ---------------- LayerNorm (fp32 in, bf16 out) ----------------
__global__ __launch_bounds__(256) void ln_kernel(const float* __restrict__ x,
                                                 const float* __restrict__ ga,
                                                 const float* __restrict__ gb,
                                                 u16* __restrict__ out) {
    int row = blockIdx.x;
    const float4* xr = (const float4*)(x + (size_t)row * 1024);
    float4 v = xr[threadIdx.x];
    float s  = v.x + v.y + v.z + v.w;
    float s2 = v.x * v.x + v.y * v.y + v.z * v.z + v.w * v.w;
#pragma unroll
    for (int off = 32; off; off >>= 1) {
        s  += __shfl_down(s, off);
        s2 += __shfl_down(s2, off);
    }
    __shared__ float rs[4], rs2[4];
    int wid = threadIdx.x >> 6, lane = threadIdx.x & 63;
    if (lane == 0) { rs[wid] = s; rs2[wid] = s2; }
    __syncthreads();
    float S  = rs[0] + rs[1] + rs[2] + rs[3];
    float S2 = rs2[0] + rs2[1] + rs2[2] + rs2[3];
    float mean = S * (1.0f / 1024.0f);
    float var  = fmaxf((S2 - 1024.0f * mean * mean) * (1.0f / 1023.0f), 0.0f);
    float scale = ga[0] / (sqrtf(var) + 1e-6f);
    float shift = gb[0] - mean * scale;
    u16 h0 = f2bf(v.x * scale + shift);
    u16 h1 = f2bf(v.y * scale + shift);
    u16 h2 = f2bf(v.z * scale + shift);
    u16 h3 = f2bf(v.w * scale + shift);
    uint2 pv;
    pv.x = (u32)h0 | ((u32)h1 << 16);
    pv.y = (u32)h2 | ((u32)h3 << 16);
    *(uint2*)(out + (size_t)row * 1024 + threadIdx.x * 4) = pv;
}

// ---------------- bias concat ----------------
__global__ __launch_bounds__(256) void bias3_kernel(const float* __restrict__ a,
                                                    const float* __restrict__ b,
                                                    const float* __restrict__ c,
                                                    float* __restrict__ d) {
    int i = blockIdx.x * 256 + threadIdx.x;
    float v = (i < 1024) ? a[i] : ((i < 2048) ? b[i - 1024] : c[i - 2048]);
    d[i] = v;
}

// ---------------- fused reduce: dst = dst + p + bias[col] + resid ----------------
__global__ __launch_bounds__(256) void addbias_kernel(float* __restrict__ dst,
                                                      const float* __restrict__ p,
                                                      const float* __restrict__ bias,
                                                      const float* __restrict__ resid) {
    int i4 = blockIdx.x * 256 + threadIdx.x;
    float4 d  = ((const float4*)dst)[i4];
    float4 pp = ((const float4*)p)[i4];
    float4 rr = ((const float4*)resid)[i4];
    float4 bb = *(const float4*)(bias + ((i4 * 4) & 1023));
    d.x += pp.x + bb.x + rr.x;
    d.y += pp.y + bb.y + rr.y;
    d.z += pp.z + bb.z + rr.z;
    d.w += pp.w + bb.w + rr.w;
    ((float4*)dst)[i4] = d;
}

// ---------------- bf16 GEMM, 2-phase double-buffered, optional split-K ----------------
template <int MODE, int RELU, int RESID>
__global__ __launch_bounds__(256) void gemm_bt(const u16* __restrict__ A,
                                               const u16* __restrict__ Bt,
                                               const float* __restrict__ bias,
                                               void* __restrict__ C0,
                                               void* __restrict__ C1,
                                               const float* __restrict__ resid,
                                               int M, int N, int K, int kLen) {
    __shared__ u16 As[8192];
    __shared__ u16 Bs[8192];
    int tid = threadIdx.x, lane = tid & 63, wid = tid >> 6;
    int l15 = lane & 15, l4 = lane >> 4;
    int rowA0 = blockIdx.x * 128;
    int rowB0 = blockIdx.y * 128;
    int kOff = blockIdx.z * kLen;
    void* Cout = blockIdx.z ? C1 : C0;
    int waveM = wid >> 1, waveN = wid & 1;

    int fl = tid * 8;
    int r0 = fl >> 5, c0 = fl & 31;
    const u16* gA0 = A + (size_t)(rowA0 + r0) * K + c0 + kOff;
    const u16* gA1 = A + (size_t)(rowA0 + 64 + r0) * K + c0 + kOff;
    const u16* gB0 = Bt + (size_t)(rowB0 + r0) * K + c0 + kOff;
    const u16* gB1 = Bt + (size_t)(rowB0 + 64 + r0) * K + c0 + kOff;

    f32x4 acc[4][4] = {};
    const int nIter = kLen >> 5;

    async_load16(gA0, As + wid * 512);
    async_load16(gA1, As + 2048 + wid * 512);
    async_load16(gB0, Bs + wid * 512);
    async_load16(gB1, Bs + 2048 + wid * 512);

    int cur = 0, kb = 32;
    for (int it = 0; it < nIter; ++it) {
        asm volatile("s_waitcnt vmcnt(0)" ::: "memory");
        __builtin_amdgcn_s_barrier();
        if (it + 1 < nIter) {
            u16* a = As + (cur ^ 1) * 4096;
            u16* bb = Bs + (cur ^ 1) * 4096;
            async_load16(gA0 + kb, a + wid * 512);
            async_load16(gA1 + kb, a + 2048 + wid * 512);
            async_load16(gB0 + kb, bb + wid * 512);
            async_load16(gB1 + kb, bb + 2048 + wid * 512);
        }
        __builtin_amdgcn_sched_barrier(0);

        const u16* a = As + cur * 4096;
        const u16* bb = Bs + cur * 4096;
        short8 af[4], bf[4];
#pragma unroll
        for (int m = 0; m < 4; m++)
            af[m] = *(const short8*)&a[(waveM * 64 + m * 16 + l15) * 32 + l4 * 8];
#pragma unroll
        for (int n = 0; n < 4; n++)
            bf[n] = *(const short8*)&bb[(waveN * 64 + n * 16 + l15) * 32 + l4 * 8];
#pragma unroll
        for (int m = 0; m < 4; m++)
#pragma unroll
            for (int n = 0; n < 4; n++)
                acc[m][n] = __builtin_amdgcn_mfma_f32_16x16x32_bf16(af[m], bf[n], acc[m][n], 0, 0, 0);

        __builtin_amdgcn_s_barrier();
        cur ^= 1;
        kb += 32;
    }

#pragma unroll
    for (int m = 0; m < 4; m++) {
        int row = rowA0 + waveM * 64 + m * 16 + l4 * 4;
#pragma unroll
        for (int n = 0; n < 4; n++) {
            int col = rowB0 + waveN * 64 + n * 16 + l15;
            float bc = (MODE == 2) ? 0.0f : bias[col];
#pragma unroll
            for (int j = 0; j < 4; j++) {
                float v = acc[m][n][j] + bc;
                if (RELU) v = fmaxf(v, 0.0f);
                if (RESID) v += resid[(size_t)(row + j) * N + col];
                if (MODE == 1)
                    ((u16*)Cout)[(size_t)(row + j) * N + col] = f2bf(v);
                else
                    ((float*)Cout)[(size_t)(row + j) * N + col] = v;
            }
        }
    }
}

// ---------------- flash attention v4: swapped QK^T, scalar softmax state, packed P ----------------
// mfma(K,Q): lane owns q-row l15, 16 s-positions {kc*16 + l4*4 + j}. Scores kept RAW;
// p = exp2((sc-m)*C), C = 0.125*log2e. Deferred-max threshold 64 raw = e^8.
__global__ __launch_bounds__(256) void attn_kernel(const u16* __restrict__ qkv,
                                                   const u16* __restrict__ vT,
                                                   const int* __restrict__ mask,
                                                   u16* __restrict__ ctx) {
    const int S = 2048;
    const float C = 0.180336880f;  // 0.125 * log2(e)
    int qt = blockIdx.x;
    int bh = blockIdx.y;
    int b = bh >> 4, h = bh & 15;
    int tid = threadIdx.x;
    int wid = tid >> 6, lane = tid & 63;
    int l15 = lane & 15, l4 = lane >> 4;

    __shared__ u16 Ks[64][72];
    __shared__ u16 Vs[64][72];
    __shared__ u32 PT[4][16][38];  // per-wave: [q-row][s-pair], stride 38 => <=2-way banks
    __shared__ int mflag;

    if (tid == 0) mflag = 1;
    __syncthreads();
    {
        const int* mrow = mask + b * S;
        int ok = 1;
#pragma unroll
        for (int i = 0; i < 8; i++) ok &= (mrow[tid * 8 + i] != 0);
        if (!ok) mflag = 0;
    }

    int qrow0 = qt * 64 + wid * 16;
    const u16* qb = qkv + (size_t)(b * S + qrow0) * 3072 + h * 64;
    short8 qf0 = *(const short8*)(qb + (size_t)l15 * 3072 + l4 * 8);
    short8 qf1 = *(const short8*)(qb + (size_t)l15 * 3072 + 32 + l4 * 8);

    f32x4 o[4] = {};
    float m_i = -1e30f, lp = 0.0f;
    __syncthreads();
    const int allones = mflag;
    const int* mrow = mask + b * S;

    int srow = tid >> 3, c8 = (tid & 7) * 8;
    short8 kreg[2], vreg[2];
#pragma unroll
    for (int p = 0; p < 2; p++) {
        int r = p * 32 + srow;
        kreg[p] = *(const short8*)(qkv + (size_t)(b * S + r) * 3072 + 1024 + h * 64 + c8);
        vreg[p] = *(const short8*)(vT + (size_t)(bh * 64 + r) * 2048 + c8);
    }

    for (int kt = 0; kt < 32; ++kt) {
        __builtin_amdgcn_s_barrier();
#pragma unroll
        for (int p = 0; p < 2; p++) {
            int r = p * 32 + srow;
            *(short8*)&Ks[r][c8] = kreg[p];
            *(short8*)&Vs[r][c8] = vreg[p];
        }
        if (kt + 1 < 32) {
#pragma unroll
            for (int p = 0; p < 2; p++) {
                int r = p * 32 + srow;
                kreg[p] = *(const short8*)(qkv + (size_t)(b * S + (kt + 1) * 64 + r) * 3072 + 1024 + h * 64 + c8);
                vreg[p] = *(const short8*)(vT + (size_t)(bh * 64 + r) * 2048 + (kt + 1) * 64 + c8);
            }
        }
        asm volatile("s_waitcnt lgkmcnt(0)" ::: "memory");
        __builtin_amdgcn_s_barrier();

        // swapped QK^T: sc[kc][j] raw; lane: q = l15, s = kt*64 + kc*16 + l4*4 + j
        float sc[4][4];
#pragma unroll
        for (int kc = 0; kc < 4; kc++) {
            short8 kf0 = *(const short8*)&Ks[kc * 16 + l15][l4 * 8];
            short8 kf1 = *(const short8*)&Ks[kc * 16 + l15][32 + l4 * 8];
            f32x4 a = {};
            a = __builtin_amdgcn_mfma_f32_16x16x32_bf16(kf0, qf0, a, 0, 0, 0);
            a = __builtin_amdgcn_mfma_f32_16x16x32_bf16(kf1, qf1, a, 0, 0, 0);
            if (allones) {
#pragma unroll
                for (int j = 0; j < 4; j++) sc[kc][j] = a[j];
            } else {
#pragma unroll
                for (int j = 0; j < 4; j++) {
                    int mk = mrow[kt * 64 + kc * 16 + l4 * 4 + j];
                    sc[kc][j] = mk ? a[j] : -1e9f;
                }
            }
        }

        // deferred-max (raw threshold 64 = 8 nats)
        float lm = sc[0][0];
#pragma unroll
        for (int kc = 0; kc < 4; kc++)
#pragma unroll
            for (int j = 0; j < 4; j++) lm = fmaxf(lm, sc[kc][j]);
        if (!__all(lm <= m_i + 64.0f)) {
            float t = lm;
            t = fmaxf(t, __shfl_xor(t, 16));
            t = fmaxf(t, __shfl_xor(t, 32));
            float newm = fmaxf(m_i, t);
            float r = exp2fast((m_i - newm) * C);
            lp *= r;
            float rr0 = __shfl(r, l4 * 4 + 0);
            float rr1 = __shfl(r, l4 * 4 + 1);
            float rr2 = __shfl(r, l4 * 4 + 2);
            float rr3 = __shfl(r, l4 * 4 + 3);
#pragma unroll
            for (int dc = 0; dc < 4; dc++) {
                o[dc][0] *= rr0; o[dc][1] *= rr1; o[dc][2] *= rr2; o[dc][3] *= rr3;
            }
            m_i = newm;
        }

        // p = exp2(sc*C - m*C); pack pairs with v_cvt_pk_bf16_f32; 4x ds_write_b64
        float nb = -m_i * C;
#pragma unroll
        for (int kc = 0; kc < 4; kc++) {
            float p0 = exp2fast(fmaf(sc[kc][0], C, nb));
            float p1 = exp2fast(fmaf(sc[kc][1], C, nb));
            float p2 = exp2fast(fmaf(sc[kc][2], C, nb));
            float p3 = exp2fast(fmaf(sc[kc][3], C, nb));
            lp += (p0 + p1) + (p2 + p3);
            uint2 w;
            w.x = cvtpk(p0, p1);
            w.y = cvtpk(p2, p3);
            *(uint2*)&PT[wid][l15][kc * 8 + l4 * 2] = w;
        }

        // A-frags: lane needs P[q=l15][s = l4*8 + 0..7] (+32 for second half)
        uint2 r01 = *(const uint2*)&PT[wid][l15][l4 * 4];
        uint2 r23 = *(const uint2*)&PT[wid][l15][l4 * 4 + 2];
        uint2 r45 = *(const uint2*)&PT[wid][l15][16 + l4 * 4];
        uint2 r67 = *(const uint2*)&PT[wid][l15][16 + l4 * 4 + 2];
        u32x4 w0 = {r01.x, r01.y, r23.x, r23.y};
        u32x4 w1 = {r45.x, r45.y, r67.x, r67.y};
        short8 pa0 = __builtin_bit_cast(short8, w0);
        short8 pa1 = __builtin_bit_cast(short8, w1);

#pragma unroll
        for (int dc = 0; dc < 4; dc++) {
            short8 vf0 = *(const short8*)&Vs[dc * 16 + l15][l4 * 8];
            short8 vf1 = *(const short8*)&Vs[dc * 16 + l15][32 + l4 * 8];
            o[dc] = __builtin_amdgcn_mfma_f32_16x16x32_bf16(pa0, vf0, o[dc], 0, 0, 0);
            o[dc] = __builtin_amdgcn_mfma_f32_16x16x32_bf16(pa1, vf1, o[dc], 0, 0, 0);
        }
    }

    // finalize: total row-sum lives across the 4-lane l4 group of lane l15
    float lt = lp;
    lt += __shfl_xor(lt, 16);
    lt += __shfl_xor(lt, 32);
    float inv = 1.0f / lt;
    float iv0 = __shfl(inv, l4 * 4 + 0);
    float iv1 = __shfl(inv, l4 * 4 + 1);
    float iv2 = __shfl(inv, l4 * 4 + 2);
    float iv3 = __shfl(inv, l4 * 4 + 3);
#pragma unroll
    for (int j = 0; j < 4; j++) {
        float ivj = (j == 0) ? iv0 : (j == 1) ? iv1 : (j == 2) ? iv2 : iv3;
        int row = qrow0 + l4 * 4 + j;
        size_t base = (size_t)(b * S + row) * 1024 + h * 64;
#pragma unroll
        for (int dc = 0; dc < 4; dc++)
            ctx[base + dc * 16 + l15] = f2bf(o[dc][j] * ivj);
    }
}

// ---------------- launcher ----------------
extern "C" void kernel_launch(void* const* d_in, const int* in_sizes, int n_in,
                              void* d_out, int out_size, void* d_ws, size_t ws_size,
                              hipStream_t stream) {
    const float* x    = (const float*)d_in[0];
    const int*   mask = (const int*)d_in[1];
    const float* wq   = (const float*)d_in[2];
    const float* bq   = (const float*)d_in[3];
    const float* wk   = (const float*)d_in[4];
    const float* bk   = (const float*)d_in[5];
    const float* wv   = (const float*)d_in[6];
    const float* bv   = (const float*)d_in[7];
    const float* wo   = (const float*)d_in[8];
    const float* bo   = (const float*)d_in[9];
    const float* w1   = (const float*)d_in[10];
    const float* b1   = (const float*)d_in[11];
    const float* w2   = (const float*)d_in[12];
    const float* b2   = (const float*)d_in[13];
    const float* ln1a = (const float*)d_in[14];
    const float* ln1b = (const float*)d_in[15];
    const float* ln2a = (const float*)d_in[16];
    const float* ln2b = (const float*)d_in[17];
    float* out = (float*)d_out;

    char* ws = (char*)d_ws;
    u16*   wqkvt = (u16*)(ws + 0);            //  6 MB
    u16*   wot   = (u16*)(ws + 6291456);      //  2 MB
    u16*   w1t   = (u16*)(ws + 8388608);      //  8 MB
    u16*   w2t   = (u16*)(ws + 16777216);     //  8 MB
    float* bqkv  = (float*)(ws + 25165824);   // 12 KB
    char*  regA  = ws + 26214400;
    u16*   xn1   = (u16*)(regA + 0);          //  8 MB
    u16*   vT    = (u16*)(regA + 0);          //  8 MB (aliases xn1)
    u16*   qkv   = (u16*)(regA + 8388608);    // 24 MB
    u16*   ctx   = (u16*)(regA + 33554432);   //  8 MB
    float* p0wo  = (float*)(regA + 0);        // 16 MB (vT+qkv dead by WO time)
    float* x1    = (float*)(ws + 68157440);   // 16 MB
    u16*   xn2   = (u16*)(regA + 0);          //  8 MB
    u16*   ff1   = (u16*)(regA + 8388608);    // 32 MB
    float* p0f2  = (float*)(ws + 0);          // 16 MB (weights dead by FFN2 time)

    dim3 blk(256);

    convt4_kernel<<<dim3(32, 32, 4), blk, 0, stream>>>(
        wq, wk, wv, wo, wqkvt, wqkvt + 1024 * 1024, wqkvt + 2048 * 1024, wot);
    convt_kernel<<<dim3(128, 32), blk, 0, stream>>>(w1, w1t, 1024, 4096);
    convt_kernel<<<dim3(32, 128), blk, 0, stream>>>(w2, w2t, 4096, 1024);
    bias3_kernel<<<dim3(12), blk, 0, stream>>>(bq, bk, bv, bqkv);

    // LN1 -> QKV -> attn -> WO (split-K=2) + reduce(+bo+x)
    ln_kernel<<<dim3(4096), blk, 0, stream>>>(x, ln1a, ln1b, xn1);
    gemm_bt<1, 0, 0><<<dim3(32, 24, 1), blk, 0, stream>>>(xn1, wqkvt, bqkv, qkv, qkv, nullptr,
                                                          4096, 3072, 1024, 1024);
    vtrans_kernel<<<dim3(64, 32, 2), blk, 0, stream>>>(qkv, vT);
    attn_kernel<<<dim3(32, 32), blk, 0, stream>>>(qkv, vT, mask, ctx);
    gemm_bt<2, 0, 0><<<dim3(32, 8, 2), blk, 0, stream>>>(ctx, wot, nullptr, p0wo, x1, nullptr,
                                                         4096, 1024, 1024, 512);
    addbias_kernel<<<dim3(4096), blk, 0, stream>>>(x1, p0wo, bo, x);

    // LN2 -> FFN1(relu) -> FFN2 (split-K=2) + reduce(+b2+x1)
    ln_kernel<<<dim3(4096), blk, 0, stream>>>(x1, ln2a, ln2b, xn2);
    gemm_bt<1, 1, 0><<<dim3(32, 32, 1), blk, 0, stream>>>(xn2, w1t, b1, ff1, ff1, nullptr,
                                                          4096, 4096, 1024, 1024);
    gemm_bt<2, 0, 0><<<dim3(32, 8, 2), blk, 0, stream>>>(ff1, w2t, nullptr, p0f2, out, nullptr,
                                                         4096, 1024, 4096, 2048);
    addbias_kernel<<<dim3(4096), blk, 0, stream>>>(out, p0f2, b2, x1);
}